// Round 1
// baseline (611.127 us; speedup 1.0000x reference)
//
#include <hip/hip_runtime.h>
#include <hip/hip_bf16.h>
#include <math.h>

#define N_NODES 50000
#define N_EDGES 800000
#define N_EP    850000   // edges + self loops
#define D 64
#define ED 32

// ws layout (float element offsets)
#define Q_OFF    0          // 3,200,000
#define K_OFF    3200000    // 3,200,000
#define V_OFF    6400000    // 3,200,000
#define W_OFF    9600000    // exp(scores): 850000*8 = 6,800,000
#define OS_OFF   16400000   // out_sum: 3,200,000
#define CNT_OFF  19600000   // 50,000
#define S_OFF    19650000   // 8
#define H_OFF    19650016   // 3,200,000
#define F1_OFF   22850016   // 6,400,000
// total = 29,250,016 floats = 117 MB

// ---------------- node QKV projection: thread per node, W in LDS ----------------
__global__ __launch_bounds__(256) void k_qkv(
    const float* __restrict__ x,
    const float* __restrict__ Wq, const float* __restrict__ bq,
    const float* __restrict__ Wk, const float* __restrict__ bk,
    const float* __restrict__ Wv, const float* __restrict__ bv,
    float* __restrict__ q, float* __restrict__ k, float* __restrict__ v) {
  __shared__ float Wl[64 * 64];
  const float* W; const float* b; float* o;
  if (blockIdx.y == 0)      { W = Wq; b = bq; o = q; }
  else if (blockIdx.y == 1) { W = Wk; b = bk; o = k; }
  else                      { W = Wv; b = bv; o = v; }
  for (int t = threadIdx.x; t < 4096; t += 256) Wl[t] = W[t];
  __syncthreads();
  const int n = blockIdx.x * 256 + threadIdx.x;
  if (n >= N_NODES) return;

  float4 acc[16];
#pragma unroll
  for (int j4 = 0; j4 < 16; ++j4) acc[j4] = make_float4(0.f, 0.f, 0.f, 0.f);
  const float4* xr = reinterpret_cast<const float4*>(x + (size_t)n * 64);
#pragma unroll 2
  for (int i4 = 0; i4 < 16; ++i4) {
    float4 xv = xr[i4];
#pragma unroll
    for (int s = 0; s < 4; ++s) {
      const float xi = (s == 0) ? xv.x : (s == 1) ? xv.y : (s == 2) ? xv.z : xv.w;
      const float4* wrow = reinterpret_cast<const float4*>(Wl + (i4 * 4 + s) * 64);
#pragma unroll
      for (int j4 = 0; j4 < 16; ++j4) {
        float4 wv = wrow[j4];
        acc[j4].x = fmaf(xi, wv.x, acc[j4].x);
        acc[j4].y = fmaf(xi, wv.y, acc[j4].y);
        acc[j4].z = fmaf(xi, wv.z, acc[j4].z);
        acc[j4].w = fmaf(xi, wv.w, acc[j4].w);
      }
    }
  }
  const float4* b4 = reinterpret_cast<const float4*>(b);
  float4* orow = reinterpret_cast<float4*>(o + (size_t)n * 64);
#pragma unroll
  for (int j4 = 0; j4 < 16; ++j4) {
    float4 a = acc[j4]; float4 bb = b4[j4];
    a.x += bb.x; a.y += bb.y; a.z += bb.z; a.w += bb.w;
    orow[j4] = a;
  }
}

// ---------------- edge pass A: scores -> w = exp(s) ----------------
__global__ __launch_bounds__(256) void k_edge_a(
    const int* __restrict__ esrc, const int* __restrict__ edst,
    const float* __restrict__ ea, const float* __restrict__ q,
    const float* __restrict__ k, const float* __restrict__ We,
    const float* __restrict__ be, float* __restrict__ wout) {
  const int lane = threadIdx.x & 63;
  const int wid = __builtin_amdgcn_readfirstlane(threadIdx.x >> 6);
  float wec[32];
#pragma unroll
  for (int i = 0; i < 32; ++i) wec[i] = We[i * 64 + lane];
  const float bel = be[lane];
  const int wstride = gridDim.x * 4;
  for (int e = blockIdx.x * 4 + wid; e < N_EP; e += wstride) {
    int s, d2; float eej;
    if (e < N_EDGES) {
      s = esrc[e]; d2 = edst[e];
      const float* ear = ea + (size_t)e * 32;
      eej = bel;
#pragma unroll
      for (int i = 0; i < 32; ++i) eej = fmaf(ear[i], wec[i], eej);
    } else {
      s = e - N_EDGES; d2 = s;
      eej = bel;
    }
    const float kj = k[(size_t)s * 64 + lane];
    const float qj = q[(size_t)d2 * 64 + lane];
    float p = qj * (kj + eej);
    p += __shfl_xor(p, 1);
    p += __shfl_xor(p, 2);
    p += __shfl_xor(p, 4);
    const float wv = __expf(p * 0.3535533905932738f);  // 1/sqrt(8)
    if ((lane & 7) == 0) wout[(size_t)e * 8 + (lane >> 3)] = wv;
  }
}

// ---------------- per-head global sum of w ----------------
__global__ __launch_bounds__(256) void k_sum(const float* __restrict__ w,
                                             float* __restrict__ S) {
  __shared__ float lds[256];
  const int tid = threadIdx.x;
  const size_t step = (size_t)gridDim.x * 256;  // multiple of 8
  float acc = 0.f;
  for (size_t i = (size_t)blockIdx.x * 256 + tid; i < (size_t)N_EP * 8; i += step)
    acc += w[i];
  lds[tid] = acc;
  __syncthreads();
  for (int s2 = 128; s2 >= 8; s2 >>= 1) {
    if (tid < s2) lds[tid] += lds[tid + s2];
    __syncthreads();
  }
  if (tid < 8) atomicAdd(&S[tid], lds[tid]);
}

// ---------------- edge pass B: scatter w*(v[src]+ee) into out_sum[dst] ----------------
__global__ __launch_bounds__(256) void k_edge_b(
    const int* __restrict__ esrc, const int* __restrict__ edst,
    const float* __restrict__ ea, const float* __restrict__ v,
    const float* __restrict__ We, const float* __restrict__ be,
    const float* __restrict__ wout, float* __restrict__ osum,
    float* __restrict__ cnt) {
  const int lane = threadIdx.x & 63;
  const int wid = __builtin_amdgcn_readfirstlane(threadIdx.x >> 6);
  float wec[32];
#pragma unroll
  for (int i = 0; i < 32; ++i) wec[i] = We[i * 64 + lane];
  const float bel = be[lane];
  const int wstride = gridDim.x * 4;
  for (int e = blockIdx.x * 4 + wid; e < N_EP; e += wstride) {
    int s, d2; float eej;
    if (e < N_EDGES) {
      s = esrc[e]; d2 = edst[e];
      const float* ear = ea + (size_t)e * 32;
      eej = bel;
#pragma unroll
      for (int i = 0; i < 32; ++i) eej = fmaf(ear[i], wec[i], eej);
    } else {
      s = e - N_EDGES; d2 = s;
      eej = bel;
    }
    const float wv = wout[(size_t)e * 8 + (lane >> 3)];
    const float vj = v[(size_t)s * 64 + lane];
    atomicAdd(&osum[(size_t)d2 * 64 + lane], wv * (vj + eej));
    if (lane == 0) atomicAdd(&cnt[d2], 1.0f);
  }
}

// ---------------- epilogue 1: out/(S*cnt) @ Wo + bo, +x, LN1 -> h ----------------
__global__ __launch_bounds__(256) void k_ln1(
    const float* __restrict__ osum, const float* __restrict__ cnt,
    const float* __restrict__ S, const float* __restrict__ x,
    const float* __restrict__ Wo, const float* __restrict__ bo,
    const float* __restrict__ g1, const float* __restrict__ b1,
    float* __restrict__ h) {
  __shared__ float Wl[64 * 64];
  for (int t = threadIdx.x; t < 4096; t += 256) Wl[t] = Wo[t];
  __syncthreads();
  const int n = blockIdx.x * 256 + threadIdx.x;
  if (n >= N_NODES) return;

  float inv[8];
#pragma unroll
  for (int hh = 0; hh < 8; ++hh) inv[hh] = 1.0f / S[hh];
  const float invc = 1.0f / cnt[n];

  float val[64];
  const float4* osr = reinterpret_cast<const float4*>(osum + (size_t)n * 64);
#pragma unroll
  for (int j4 = 0; j4 < 16; ++j4) {
    float4 t = osr[j4];
    val[j4 * 4 + 0] = t.x * inv[(j4 * 4 + 0) >> 3] * invc;
    val[j4 * 4 + 1] = t.y * inv[(j4 * 4 + 1) >> 3] * invc;
    val[j4 * 4 + 2] = t.z * inv[(j4 * 4 + 2) >> 3] * invc;
    val[j4 * 4 + 3] = t.w * inv[(j4 * 4 + 3) >> 3] * invc;
  }

  float4 acc[16];
#pragma unroll
  for (int j4 = 0; j4 < 16; ++j4) acc[j4] = make_float4(0.f, 0.f, 0.f, 0.f);
#pragma unroll 4
  for (int i = 0; i < 64; ++i) {
    const float xi = val[i];
    const float4* wrow = reinterpret_cast<const float4*>(Wl + i * 64);
#pragma unroll
    for (int j4 = 0; j4 < 16; ++j4) {
      float4 wv = wrow[j4];
      acc[j4].x = fmaf(xi, wv.x, acc[j4].x);
      acc[j4].y = fmaf(xi, wv.y, acc[j4].y);
      acc[j4].z = fmaf(xi, wv.z, acc[j4].z);
      acc[j4].w = fmaf(xi, wv.w, acc[j4].w);
    }
  }

  // t = x + proj + bo, then LN
  const float4* xr = reinterpret_cast<const float4*>(x + (size_t)n * 64);
  const float4* bo4 = reinterpret_cast<const float4*>(bo);
  float t[64];
  float m = 0.f;
#pragma unroll
  for (int j4 = 0; j4 < 16; ++j4) {
    float4 xv = xr[j4]; float4 bb = bo4[j4];
    t[j4 * 4 + 0] = xv.x + acc[j4].x + bb.x;
    t[j4 * 4 + 1] = xv.y + acc[j4].y + bb.y;
    t[j4 * 4 + 2] = xv.z + acc[j4].z + bb.z;
    t[j4 * 4 + 3] = xv.w + acc[j4].w + bb.w;
    m += t[j4 * 4 + 0] + t[j4 * 4 + 1] + t[j4 * 4 + 2] + t[j4 * 4 + 3];
  }
  m *= (1.0f / 64.0f);
  float var = 0.f;
#pragma unroll
  for (int j = 0; j < 64; ++j) { const float dt = t[j] - m; var = fmaf(dt, dt, var); }
  var *= (1.0f / 64.0f);
  const float r = rsqrtf(var + 1e-5f);
  const float4* g14 = reinterpret_cast<const float4*>(g1);
  const float4* b14 = reinterpret_cast<const float4*>(b1);
  float4* hr = reinterpret_cast<float4*>(h + (size_t)n * 64);
#pragma unroll
  for (int j4 = 0; j4 < 16; ++j4) {
    float4 g = g14[j4]; float4 bb = b14[j4]; float4 o;
    o.x = (t[j4 * 4 + 0] - m) * r * g.x + bb.x;
    o.y = (t[j4 * 4 + 1] - m) * r * g.y + bb.y;
    o.z = (t[j4 * 4 + 2] - m) * r * g.z + bb.z;
    o.w = (t[j4 * 4 + 3] - m) * r * g.w + bb.w;
    hr[j4] = o;
  }
}

// ---------------- FFN stage 1: f1 = gelu(h @ Wf1 + bf1) ----------------
__global__ __launch_bounds__(256) void k_ffn1(
    const float* __restrict__ h, const float* __restrict__ Wf1,
    const float* __restrict__ bf1, float* __restrict__ f1) {
  __shared__ float Wl[64 * 128];
  for (int t = threadIdx.x; t < 8192; t += 256) Wl[t] = Wf1[t];
  __syncthreads();
  const int n = blockIdx.x * 256 + threadIdx.x;
  if (n >= N_NODES) return;

  float4 acc[32];
#pragma unroll
  for (int j4 = 0; j4 < 32; ++j4) acc[j4] = make_float4(0.f, 0.f, 0.f, 0.f);
  const float4* xr = reinterpret_cast<const float4*>(h + (size_t)n * 64);
#pragma unroll 2
  for (int i4 = 0; i4 < 16; ++i4) {
    float4 xv = xr[i4];
#pragma unroll
    for (int s = 0; s < 4; ++s) {
      const float xi = (s == 0) ? xv.x : (s == 1) ? xv.y : (s == 2) ? xv.z : xv.w;
      const float4* wrow = reinterpret_cast<const float4*>(Wl + (i4 * 4 + s) * 128);
#pragma unroll
      for (int j4 = 0; j4 < 32; ++j4) {
        float4 wv = wrow[j4];
        acc[j4].x = fmaf(xi, wv.x, acc[j4].x);
        acc[j4].y = fmaf(xi, wv.y, acc[j4].y);
        acc[j4].z = fmaf(xi, wv.z, acc[j4].z);
        acc[j4].w = fmaf(xi, wv.w, acc[j4].w);
      }
    }
  }
  const float4* b4 = reinterpret_cast<const float4*>(bf1);
  float4* orow = reinterpret_cast<float4*>(f1 + (size_t)n * 128);
#pragma unroll
  for (int j4 = 0; j4 < 32; ++j4) {
    float4 a = acc[j4]; float4 bb = b4[j4];
    a.x += bb.x; a.y += bb.y; a.z += bb.z; a.w += bb.w;
    a.x = 0.5f * a.x * (1.0f + erff(a.x * 0.7071067811865475f));
    a.y = 0.5f * a.y * (1.0f + erff(a.y * 0.7071067811865475f));
    a.z = 0.5f * a.z * (1.0f + erff(a.z * 0.7071067811865475f));
    a.w = 0.5f * a.w * (1.0f + erff(a.w * 0.7071067811865475f));
    orow[j4] = a;
  }
}

// ---------------- FFN stage 2 + residual + LN2 -> d_out ----------------
__global__ __launch_bounds__(256) void k_ffn2(
    const float* __restrict__ f1, const float* __restrict__ h,
    const float* __restrict__ Wf2, const float* __restrict__ bf2,
    const float* __restrict__ g2, const float* __restrict__ b2,
    float* __restrict__ out) {
  __shared__ float Wl[128 * 64];
  for (int t = threadIdx.x; t < 8192; t += 256) Wl[t] = Wf2[t];
  __syncthreads();
  const int n = blockIdx.x * 256 + threadIdx.x;
  if (n >= N_NODES) return;

  float4 acc[16];
#pragma unroll
  for (int j4 = 0; j4 < 16; ++j4) acc[j4] = make_float4(0.f, 0.f, 0.f, 0.f);
  const float4* fr = reinterpret_cast<const float4*>(f1 + (size_t)n * 128);
#pragma unroll 2
  for (int i4 = 0; i4 < 32; ++i4) {
    float4 fv = fr[i4];
#pragma unroll
    for (int s = 0; s < 4; ++s) {
      const float fi = (s == 0) ? fv.x : (s == 1) ? fv.y : (s == 2) ? fv.z : fv.w;
      const float4* wrow = reinterpret_cast<const float4*>(Wl + (i4 * 4 + s) * 64);
#pragma unroll
      for (int j4 = 0; j4 < 16; ++j4) {
        float4 wv = wrow[j4];
        acc[j4].x = fmaf(fi, wv.x, acc[j4].x);
        acc[j4].y = fmaf(fi, wv.y, acc[j4].y);
        acc[j4].z = fmaf(fi, wv.z, acc[j4].z);
        acc[j4].w = fmaf(fi, wv.w, acc[j4].w);
      }
    }
  }

  const float4* hr = reinterpret_cast<const float4*>(h + (size_t)n * 64);
  const float4* b4 = reinterpret_cast<const float4*>(bf2);
  float t[64];
  float m = 0.f;
#pragma unroll
  for (int j4 = 0; j4 < 16; ++j4) {
    float4 hv = hr[j4]; float4 bb = b4[j4];
    t[j4 * 4 + 0] = hv.x + acc[j4].x + bb.x;
    t[j4 * 4 + 1] = hv.y + acc[j4].y + bb.y;
    t[j4 * 4 + 2] = hv.z + acc[j4].z + bb.z;
    t[j4 * 4 + 3] = hv.w + acc[j4].w + bb.w;
    m += t[j4 * 4 + 0] + t[j4 * 4 + 1] + t[j4 * 4 + 2] + t[j4 * 4 + 3];
  }
  m *= (1.0f / 64.0f);
  float var = 0.f;
#pragma unroll
  for (int j = 0; j < 64; ++j) { const float dt = t[j] - m; var = fmaf(dt, dt, var); }
  var *= (1.0f / 64.0f);
  const float r = rsqrtf(var + 1e-5f);
  const float4* g24 = reinterpret_cast<const float4*>(g2);
  const float4* b24 = reinterpret_cast<const float4*>(b2);
  float4* orow = reinterpret_cast<float4*>(out + (size_t)n * 64);
#pragma unroll
  for (int j4 = 0; j4 < 16; ++j4) {
    float4 g = g24[j4]; float4 bb = b24[j4]; float4 o;
    o.x = (t[j4 * 4 + 0] - m) * r * g.x + bb.x;
    o.y = (t[j4 * 4 + 1] - m) * r * g.y + bb.y;
    o.z = (t[j4 * 4 + 2] - m) * r * g.z + bb.z;
    o.w = (t[j4 * 4 + 3] - m) * r * g.w + bb.w;
    orow[j4] = o;
  }
}

extern "C" void kernel_launch(void* const* d_in, const int* in_sizes, int n_in,
                              void* d_out, int out_size, void* d_ws, size_t ws_size,
                              hipStream_t stream) {
  const float* x    = (const float*)d_in[0];
  const int*   ei   = (const int*)d_in[1];
  const int*   esrc = ei;
  const int*   edst = ei + N_EDGES;
  const float* ea   = (const float*)d_in[2];
  const float* Wq   = (const float*)d_in[3];
  const float* bq   = (const float*)d_in[4];
  const float* Wk   = (const float*)d_in[5];
  const float* bk   = (const float*)d_in[6];
  const float* Wv   = (const float*)d_in[7];
  const float* bv   = (const float*)d_in[8];
  const float* We   = (const float*)d_in[9];
  const float* be   = (const float*)d_in[10];
  const float* Wo   = (const float*)d_in[11];
  const float* bo   = (const float*)d_in[12];
  const float* g1   = (const float*)d_in[13];
  const float* b1   = (const float*)d_in[14];
  const float* g2   = (const float*)d_in[15];
  const float* b2   = (const float*)d_in[16];
  const float* Wf1  = (const float*)d_in[17];
  const float* bf1  = (const float*)d_in[18];
  const float* Wf2  = (const float*)d_in[19];
  const float* bf2  = (const float*)d_in[20];

  float* ws   = (float*)d_ws;
  float* q    = ws + Q_OFF;
  float* k    = ws + K_OFF;
  float* v    = ws + V_OFF;
  float* w    = ws + W_OFF;
  float* osum = ws + OS_OFF;
  float* cnt  = ws + CNT_OFF;
  float* S    = ws + S_OFF;
  float* h    = ws + H_OFF;
  float* f1   = ws + F1_OFF;
  float* out  = (float*)d_out;

  // zero the accumulators (osum, cnt, S are contiguous)
  hipMemsetAsync(osum, 0, (size_t)(3200000 + 50000 + 8) * sizeof(float), stream);

  const dim3 B(256);
  const int nodeBlocks = (N_NODES + 255) / 256;  // 196

  k_qkv<<<dim3(nodeBlocks, 3), B, 0, stream>>>(x, Wq, bq, Wk, bk, Wv, bv, q, k, v);
  k_edge_a<<<dim3(8192), B, 0, stream>>>(esrc, edst, ea, q, k, We, be, w);
  k_sum<<<dim3(256), B, 0, stream>>>(w, S);
  k_edge_b<<<dim3(8192), B, 0, stream>>>(esrc, edst, ea, v, We, be, w, osum, cnt);
  k_ln1<<<dim3(nodeBlocks), B, 0, stream>>>(osum, cnt, S, x, Wo, bo, g1, b1, h);
  k_ffn1<<<dim3(nodeBlocks), B, 0, stream>>>(h, Wf1, bf1, f1);
  k_ffn2<<<dim3(nodeBlocks), B, 0, stream>>>(f1, h, Wf2, bf2, g2, b2, out);
}

// Round 2
// 512.088 us; speedup vs baseline: 1.1934x; 1.1934x over previous
//
#include <hip/hip_runtime.h>
#include <hip/hip_bf16.h>
#include <math.h>

#define N_NODES 50000
#define N_EDGES 800000
#define N_EP    850000   // edges + self loops
#define D 64
#define ED 32

// ws layout (float element offsets)
#define Q_OFF    0          // 3,200,000
#define K_OFF    3200000    // 3,200,000
#define V_OFF    6400000    // 3,200,000
#define OS_OFF   9600000    // out_sum: 3,200,000
#define CNT_OFF  12800000   // 50,000
#define S_OFF    12850000   // 8 (+8 pad)
#define H_OFF    12850016   // 3,200,000
#define F1_OFF   16050016   // 6,400,000
// total = 22,450,016 floats ~ 90 MB

// ---------------- node QKV projection: thread per node, W in LDS ----------------
__global__ __launch_bounds__(256) void k_qkv(
    const float* __restrict__ x,
    const float* __restrict__ Wq, const float* __restrict__ bq,
    const float* __restrict__ Wk, const float* __restrict__ bk,
    const float* __restrict__ Wv, const float* __restrict__ bv,
    float* __restrict__ q, float* __restrict__ k, float* __restrict__ v) {
  __shared__ float Wl[64 * 64];
  const float* W; const float* b; float* o;
  if (blockIdx.y == 0)      { W = Wq; b = bq; o = q; }
  else if (blockIdx.y == 1) { W = Wk; b = bk; o = k; }
  else                      { W = Wv; b = bv; o = v; }
  for (int t = threadIdx.x; t < 4096; t += 256) Wl[t] = W[t];
  __syncthreads();
  const int n = blockIdx.x * 256 + threadIdx.x;
  if (n >= N_NODES) return;

  float4 acc[16];
#pragma unroll
  for (int j4 = 0; j4 < 16; ++j4) acc[j4] = make_float4(0.f, 0.f, 0.f, 0.f);
  const float4* xr = reinterpret_cast<const float4*>(x + (size_t)n * 64);
#pragma unroll 2
  for (int i4 = 0; i4 < 16; ++i4) {
    float4 xv = xr[i4];
#pragma unroll
    for (int s = 0; s < 4; ++s) {
      const float xi = (s == 0) ? xv.x : (s == 1) ? xv.y : (s == 2) ? xv.z : xv.w;
      const float4* wrow = reinterpret_cast<const float4*>(Wl + (i4 * 4 + s) * 64);
#pragma unroll
      for (int j4 = 0; j4 < 16; ++j4) {
        float4 wv = wrow[j4];
        acc[j4].x = fmaf(xi, wv.x, acc[j4].x);
        acc[j4].y = fmaf(xi, wv.y, acc[j4].y);
        acc[j4].z = fmaf(xi, wv.z, acc[j4].z);
        acc[j4].w = fmaf(xi, wv.w, acc[j4].w);
      }
    }
  }
  const float4* b4 = reinterpret_cast<const float4*>(b);
  float4* orow = reinterpret_cast<float4*>(o + (size_t)n * 64);
#pragma unroll
  for (int j4 = 0; j4 < 16; ++j4) {
    float4 a = acc[j4]; float4 bb = b4[j4];
    a.x += bb.x; a.y += bb.y; a.z += bb.z; a.w += bb.w;
    orow[j4] = a;
  }
}

// ---------------- fused edge kernel: score -> w=exp -> scatter, S partials ----------------
// One wave per edge; ea staged through LDS in 256-edge chunks.
__global__ __launch_bounds__(256) void k_edge(
    const int* __restrict__ esrc, const int* __restrict__ edst,
    const float* __restrict__ ea, const float* __restrict__ q,
    const float* __restrict__ k, const float* __restrict__ v,
    const float* __restrict__ We, const float* __restrict__ be,
    float* __restrict__ osum, float* __restrict__ cnt,
    float* __restrict__ S) {
  __shared__ float eas[256 * 32];   // 32 KB: ea rows for the chunk
  __shared__ int   ss[256], dd[256];
  const int lane = threadIdx.x & 63;
  const int wid  = threadIdx.x >> 6;

  float wec[32];
#pragma unroll
  for (int i = 0; i < 32; ++i) wec[i] = We[i * 64 + lane];
  const float bel = be[lane];
  float sacc = 0.f;  // per-thread partial of S[lane>>3] (only (lane&7)==0 flushes)

  const int nchunks = N_EDGES / 256;  // 3125 exactly
  for (int c = blockIdx.x; c < nchunks; c += gridDim.x) {
    const int base = c * 256;
    __syncthreads();  // protect previous chunk's LDS reads
    {
      const float4* g = reinterpret_cast<const float4*>(ea + (size_t)base * 32);
      float4* l = reinterpret_cast<float4*>(eas);
#pragma unroll
      for (int t = 0; t < 8; ++t) l[threadIdx.x + t * 256] = g[threadIdx.x + t * 256];
      ss[threadIdx.x] = esrc[base + threadIdx.x];
      dd[threadIdx.x] = edst[base + threadIdx.x];
    }
    __syncthreads();

    for (int j = 0; j < 64; ++j) {
      const int le = wid * 64 + j;
      const int s  = ss[le];
      const int d2 = dd[le];
      float eej = bel;
      const float4* er = reinterpret_cast<const float4*>(eas + le * 32);
#pragma unroll
      for (int i4 = 0; i4 < 8; ++i4) {
        float4 t = er[i4];
        eej = fmaf(t.x, wec[i4 * 4 + 0], eej);
        eej = fmaf(t.y, wec[i4 * 4 + 1], eej);
        eej = fmaf(t.z, wec[i4 * 4 + 2], eej);
        eej = fmaf(t.w, wec[i4 * 4 + 3], eej);
      }
      const float kj = k[(size_t)s * 64 + lane];
      const float qj = q[(size_t)d2 * 64 + lane];
      const float vj = v[(size_t)s * 64 + lane];
      float p = qj * (kj + eej);
      p += __shfl_xor(p, 1);
      p += __shfl_xor(p, 2);
      p += __shfl_xor(p, 4);
      const float wv = __expf(p * 0.3535533905932738f);  // 1/sqrt(8)
      if ((lane & 7) == 0) sacc += wv;
      atomicAdd(&osum[(size_t)d2 * 64 + lane], wv * (vj + eej));
      if (lane == 0) atomicAdd(&cnt[d2], 1.0f);
    }
  }

  // self-loop edges: e in [N_EDGES, N_EP), src=dst=n, ea=0 -> ee=be
  const int wstride = gridDim.x * 4;
  for (int n = blockIdx.x * 4 + wid; n < N_NODES; n += wstride) {
    const float eej = bel;
    const float kj = k[(size_t)n * 64 + lane];
    const float qj = q[(size_t)n * 64 + lane];
    const float vj = v[(size_t)n * 64 + lane];
    float p = qj * (kj + eej);
    p += __shfl_xor(p, 1);
    p += __shfl_xor(p, 2);
    p += __shfl_xor(p, 4);
    const float wv = __expf(p * 0.3535533905932738f);
    if ((lane & 7) == 0) sacc += wv;
    atomicAdd(&osum[(size_t)n * 64 + lane], wv * (vj + eej));
    if (lane == 0) atomicAdd(&cnt[n], 1.0f);
  }

  if ((lane & 7) == 0) atomicAdd(&S[lane >> 3], sacc);
}

// ---------------- epilogue 1: out/(S*cnt) @ Wo + bo, +x, LN1 -> h ----------------
__global__ __launch_bounds__(256) void k_ln1(
    const float* __restrict__ osum, const float* __restrict__ cnt,
    const float* __restrict__ S, const float* __restrict__ x,
    const float* __restrict__ Wo, const float* __restrict__ bo,
    const float* __restrict__ g1, const float* __restrict__ b1,
    float* __restrict__ h) {
  __shared__ float Wl[64 * 64];
  for (int t = threadIdx.x; t < 4096; t += 256) Wl[t] = Wo[t];
  __syncthreads();
  const int n = blockIdx.x * 256 + threadIdx.x;
  if (n >= N_NODES) return;

  float inv[8];
#pragma unroll
  for (int hh = 0; hh < 8; ++hh) inv[hh] = 1.0f / S[hh];
  const float invc = 1.0f / cnt[n];

  float val[64];
  const float4* osr = reinterpret_cast<const float4*>(osum + (size_t)n * 64);
#pragma unroll
  for (int j4 = 0; j4 < 16; ++j4) {
    float4 t = osr[j4];
    val[j4 * 4 + 0] = t.x * inv[(j4 * 4 + 0) >> 3] * invc;
    val[j4 * 4 + 1] = t.y * inv[(j4 * 4 + 1) >> 3] * invc;
    val[j4 * 4 + 2] = t.z * inv[(j4 * 4 + 2) >> 3] * invc;
    val[j4 * 4 + 3] = t.w * inv[(j4 * 4 + 3) >> 3] * invc;
  }

  float4 acc[16];
#pragma unroll
  for (int j4 = 0; j4 < 16; ++j4) acc[j4] = make_float4(0.f, 0.f, 0.f, 0.f);
#pragma unroll 4
  for (int i = 0; i < 64; ++i) {
    const float xi = val[i];
    const float4* wrow = reinterpret_cast<const float4*>(Wl + i * 64);
#pragma unroll
    for (int j4 = 0; j4 < 16; ++j4) {
      float4 wv = wrow[j4];
      acc[j4].x = fmaf(xi, wv.x, acc[j4].x);
      acc[j4].y = fmaf(xi, wv.y, acc[j4].y);
      acc[j4].z = fmaf(xi, wv.z, acc[j4].z);
      acc[j4].w = fmaf(xi, wv.w, acc[j4].w);
    }
  }

  const float4* xr = reinterpret_cast<const float4*>(x + (size_t)n * 64);
  const float4* bo4 = reinterpret_cast<const float4*>(bo);
  float t[64];
  float m = 0.f;
#pragma unroll
  for (int j4 = 0; j4 < 16; ++j4) {
    float4 xv = xr[j4]; float4 bb = bo4[j4];
    t[j4 * 4 + 0] = xv.x + acc[j4].x + bb.x;
    t[j4 * 4 + 1] = xv.y + acc[j4].y + bb.y;
    t[j4 * 4 + 2] = xv.z + acc[j4].z + bb.z;
    t[j4 * 4 + 3] = xv.w + acc[j4].w + bb.w;
    m += t[j4 * 4 + 0] + t[j4 * 4 + 1] + t[j4 * 4 + 2] + t[j4 * 4 + 3];
  }
  m *= (1.0f / 64.0f);
  float var = 0.f;
#pragma unroll
  for (int j = 0; j < 64; ++j) { const float dt = t[j] - m; var = fmaf(dt, dt, var); }
  var *= (1.0f / 64.0f);
  const float r = rsqrtf(var + 1e-5f);
  const float4* g14 = reinterpret_cast<const float4*>(g1);
  const float4* b14 = reinterpret_cast<const float4*>(b1);
  float4* hr = reinterpret_cast<float4*>(h + (size_t)n * 64);
#pragma unroll
  for (int j4 = 0; j4 < 16; ++j4) {
    float4 g = g14[j4]; float4 bb = b14[j4]; float4 o;
    o.x = (t[j4 * 4 + 0] - m) * r * g.x + bb.x;
    o.y = (t[j4 * 4 + 1] - m) * r * g.y + bb.y;
    o.z = (t[j4 * 4 + 2] - m) * r * g.z + bb.z;
    o.w = (t[j4 * 4 + 3] - m) * r * g.w + bb.w;
    hr[j4] = o;
  }
}

// ---------------- FFN stage 1: f1 = gelu(h @ Wf1 + bf1) ----------------
__global__ __launch_bounds__(256) void k_ffn1(
    const float* __restrict__ h, const float* __restrict__ Wf1,
    const float* __restrict__ bf1, float* __restrict__ f1) {
  __shared__ float Wl[64 * 128];
  for (int t = threadIdx.x; t < 8192; t += 256) Wl[t] = Wf1[t];
  __syncthreads();
  const int n = blockIdx.x * 256 + threadIdx.x;
  if (n >= N_NODES) return;

  float4 acc[32];
#pragma unroll
  for (int j4 = 0; j4 < 32; ++j4) acc[j4] = make_float4(0.f, 0.f, 0.f, 0.f);
  const float4* xr = reinterpret_cast<const float4*>(h + (size_t)n * 64);
#pragma unroll 2
  for (int i4 = 0; i4 < 16; ++i4) {
    float4 xv = xr[i4];
#pragma unroll
    for (int s = 0; s < 4; ++s) {
      const float xi = (s == 0) ? xv.x : (s == 1) ? xv.y : (s == 2) ? xv.z : xv.w;
      const float4* wrow = reinterpret_cast<const float4*>(Wl + (i4 * 4 + s) * 128);
#pragma unroll
      for (int j4 = 0; j4 < 32; ++j4) {
        float4 wv = wrow[j4];
        acc[j4].x = fmaf(xi, wv.x, acc[j4].x);
        acc[j4].y = fmaf(xi, wv.y, acc[j4].y);
        acc[j4].z = fmaf(xi, wv.z, acc[j4].z);
        acc[j4].w = fmaf(xi, wv.w, acc[j4].w);
      }
    }
  }
  const float4* b4 = reinterpret_cast<const float4*>(bf1);
  float4* orow = reinterpret_cast<float4*>(f1 + (size_t)n * 128);
#pragma unroll
  for (int j4 = 0; j4 < 32; ++j4) {
    float4 a = acc[j4]; float4 bb = b4[j4];
    a.x += bb.x; a.y += bb.y; a.z += bb.z; a.w += bb.w;
    a.x = 0.5f * a.x * (1.0f + erff(a.x * 0.7071067811865475f));
    a.y = 0.5f * a.y * (1.0f + erff(a.y * 0.7071067811865475f));
    a.z = 0.5f * a.z * (1.0f + erff(a.z * 0.7071067811865475f));
    a.w = 0.5f * a.w * (1.0f + erff(a.w * 0.7071067811865475f));
    orow[j4] = a;
  }
}

// ---------------- FFN stage 2 + residual + LN2 -> d_out ----------------
__global__ __launch_bounds__(256) void k_ffn2(
    const float* __restrict__ f1, const float* __restrict__ h,
    const float* __restrict__ Wf2, const float* __restrict__ bf2,
    const float* __restrict__ g2, const float* __restrict__ b2,
    float* __restrict__ out) {
  __shared__ float Wl[128 * 64];
  for (int t = threadIdx.x; t < 8192; t += 256) Wl[t] = Wf2[t];
  __syncthreads();
  const int n = blockIdx.x * 256 + threadIdx.x;
  if (n >= N_NODES) return;

  float4 acc[16];
#pragma unroll
  for (int j4 = 0; j4 < 16; ++j4) acc[j4] = make_float4(0.f, 0.f, 0.f, 0.f);
  const float4* fr = reinterpret_cast<const float4*>(f1 + (size_t)n * 128);
#pragma unroll 2
  for (int i4 = 0; i4 < 32; ++i4) {
    float4 fv = fr[i4];
#pragma unroll
    for (int s = 0; s < 4; ++s) {
      const float fi = (s == 0) ? fv.x : (s == 1) ? fv.y : (s == 2) ? fv.z : fv.w;
      const float4* wrow = reinterpret_cast<const float4*>(Wl + (i4 * 4 + s) * 64);
#pragma unroll
      for (int j4 = 0; j4 < 16; ++j4) {
        float4 wv = wrow[j4];
        acc[j4].x = fmaf(fi, wv.x, acc[j4].x);
        acc[j4].y = fmaf(fi, wv.y, acc[j4].y);
        acc[j4].z = fmaf(fi, wv.z, acc[j4].z);
        acc[j4].w = fmaf(fi, wv.w, acc[j4].w);
      }
    }
  }

  const float4* hr = reinterpret_cast<const float4*>(h + (size_t)n * 64);
  const float4* b4 = reinterpret_cast<const float4*>(bf2);
  float t[64];
  float m = 0.f;
#pragma unroll
  for (int j4 = 0; j4 < 16; ++j4) {
    float4 hv = hr[j4]; float4 bb = b4[j4];
    t[j4 * 4 + 0] = hv.x + acc[j4].x + bb.x;
    t[j4 * 4 + 1] = hv.y + acc[j4].y + bb.y;
    t[j4 * 4 + 2] = hv.z + acc[j4].z + bb.z;
    t[j4 * 4 + 3] = hv.w + acc[j4].w + bb.w;
    m += t[j4 * 4 + 0] + t[j4 * 4 + 1] + t[j4 * 4 + 2] + t[j4 * 4 + 3];
  }
  m *= (1.0f / 64.0f);
  float var = 0.f;
#pragma unroll
  for (int j = 0; j < 64; ++j) { const float dt = t[j] - m; var = fmaf(dt, dt, var); }
  var *= (1.0f / 64.0f);
  const float r = rsqrtf(var + 1e-5f);
  const float4* g24 = reinterpret_cast<const float4*>(g2);
  const float4* b24 = reinterpret_cast<const float4*>(b2);
  float4* orow = reinterpret_cast<float4*>(out + (size_t)n * 64);
#pragma unroll
  for (int j4 = 0; j4 < 16; ++j4) {
    float4 g = g24[j4]; float4 bb = b24[j4]; float4 o;
    o.x = (t[j4 * 4 + 0] - m) * r * g.x + bb.x;
    o.y = (t[j4 * 4 + 1] - m) * r * g.y + bb.y;
    o.z = (t[j4 * 4 + 2] - m) * r * g.z + bb.z;
    o.w = (t[j4 * 4 + 3] - m) * r * g.w + bb.w;
    orow[j4] = o;
  }
}

extern "C" void kernel_launch(void* const* d_in, const int* in_sizes, int n_in,
                              void* d_out, int out_size, void* d_ws, size_t ws_size,
                              hipStream_t stream) {
  const float* x    = (const float*)d_in[0];
  const int*   ei   = (const int*)d_in[1];
  const int*   esrc = ei;
  const int*   edst = ei + N_EDGES;
  const float* ea   = (const float*)d_in[2];
  const float* Wq   = (const float*)d_in[3];
  const float* bq   = (const float*)d_in[4];
  const float* Wk   = (const float*)d_in[5];
  const float* bk   = (const float*)d_in[6];
  const float* Wv   = (const float*)d_in[7];
  const float* bv   = (const float*)d_in[8];
  const float* We   = (const float*)d_in[9];
  const float* be   = (const float*)d_in[10];
  const float* Wo   = (const float*)d_in[11];
  const float* bo   = (const float*)d_in[12];
  const float* g1   = (const float*)d_in[13];
  const float* b1   = (const float*)d_in[14];
  const float* g2   = (const float*)d_in[15];
  const float* b2   = (const float*)d_in[16];
  const float* Wf1  = (const float*)d_in[17];
  const float* bf1  = (const float*)d_in[18];
  const float* Wf2  = (const float*)d_in[19];
  const float* bf2  = (const float*)d_in[20];

  float* ws   = (float*)d_ws;
  float* q    = ws + Q_OFF;
  float* k    = ws + K_OFF;
  float* v    = ws + V_OFF;
  float* osum = ws + OS_OFF;
  float* cnt  = ws + CNT_OFF;
  float* S    = ws + S_OFF;
  float* h    = ws + H_OFF;
  float* f1   = ws + F1_OFF;
  float* out  = (float*)d_out;

  // zero the accumulators (osum, cnt, S are contiguous)
  hipMemsetAsync(osum, 0, (size_t)(3200000 + 50000 + 16) * sizeof(float), stream);

  const dim3 B(256);
  const int nodeBlocks = (N_NODES + 255) / 256;  // 196

  k_qkv<<<dim3(nodeBlocks, 3), B, 0, stream>>>(x, Wq, bq, Wk, bk, Wv, bv, q, k, v);
  k_edge<<<dim3(2048), B, 0, stream>>>(esrc, edst, ea, q, k, v, We, be, osum, cnt, S);
  k_ln1<<<dim3(nodeBlocks), B, 0, stream>>>(osum, cnt, S, x, Wo, bo, g1, b1, h);
  k_ffn1<<<dim3(nodeBlocks), B, 0, stream>>>(h, Wf1, bf1, f1);
  k_ffn2<<<dim3(nodeBlocks), B, 0, stream>>>(f1, h, Wf2, bf2, g2, b2, out);
}